// Round 8
// baseline (9161.208 us; speedup 1.0000x reference)
//
#include <hip/hip_runtime.h>
#include <math.h>
#include <stdint.h>

#define B 128
#define S 512
#define V 6000
#define E 100
#define H 256
#define G4 1024   /* 4*H */
#define T 9

/* W column split (float4 k-groups, 64 total = 256 cols per row) */
#define WREG 20            /* groups [0,20): pinned in VGPR (pair kernel: 80 regs, live) */
#define WLDS 3             /* groups [20,23): LDS slab */
#define WSTR 41            /* groups [23,64): prepacked k-major stream */

/* workspace byte offsets (256-aligned) */
#define OFF_PEMB_F 0u
#define PEMB_BYTES (V*G4*4u)                    /* 24,576,000 */
#define OFF_PEMB_B (OFF_PEMB_F + PEMB_BYTES)
#define OFF_EMF    (OFF_PEMB_B + PEMB_BYTES)    /* 49,152,000 */
#define EM_BYTES   (B*S*T*4u)                   /* 2,359,296 */
#define OFF_EMB    (OFF_EMF + EM_BYTES)
#define OFF_BP     (OFF_EMB + EM_BYTES)         /* 53,870,592 */
#define BP_BYTES   ((S-1)*B*16u)                /* 1,046,528 */
#define OFF_LT     (OFF_BP + BP_BYTES)
#define OFF_PT     (OFF_LT + 512u)
/* Streamed-W (2 dirs x 41 groups x 1024 rows x 16 B = 1,343,488 B) OVERLAYS
   the BP/LT/PT region (k_prep writes, k_lstm reads BEFORE k_vit/k_back write). */
#define OFF_WSTREAM OFF_BP
/* R8 pair-exchange buffers, AFTER the proven wstr end — used only if ws_size
   covers them (adaptive fallback otherwise). hx[par][job][q][bi][128] f32. */
#define OFF_HX  (OFF_BP + 1343488u)             /* 55,214,080 */
#define HX_BYTES (2u*128u*2u*2u*128u*4u)        /* 524,288 */
#define OFF_FLG (OFF_HX + HX_BYTES)
#define FLG_BYTES (256u*4u)
#define WS_NEED ((size_t)OFF_FLG + FLG_BYTES)   /* 55,739,392 */

__device__ __forceinline__ float sigf(float x) { return 1.0f / (1.0f + expf(-x)); }

/* pemb[v][g4] = bias[g4] + sum_e emb[v][e] * W_ih[g4][e],  g4 = q*H + j */
__global__ __launch_bounds__(256) void k_pemb(const float* __restrict__ emb,
                                              const float* __restrict__ wf, const float* __restrict__ bf,
                                              const float* __restrict__ wb, const float* __restrict__ bb,
                                              char* __restrict__ ws) {
    int blk = blockIdx.x;                   /* 0..749 */
    int d   = blk >= 375;
    int vb  = d ? blk - 375 : blk;
    const float* W    = d ? wb : wf;
    const float* bias = d ? bb : bf;
    float* pe = (float*)(ws + (d ? OFF_PEMB_B : OFF_PEMB_F));

    __shared__ float es[16 * E];
    for (int i = threadIdx.x; i < 16 * E; i += 256) es[i] = emb[vb * 16 * E + i];
    __syncthreads();

    int j = threadIdx.x;
    float acc[4][16];
    #pragma unroll
    for (int q = 0; q < 4; q++) {
        float bq = bias[q * H + j];
        #pragma unroll
        for (int v = 0; v < 16; v++) acc[q][v] = bq;
    }
    for (int e = 0; e < E; e++) {
        float w0 = W[(0 * H + j) * E + e];
        float w1 = W[(1 * H + j) * E + e];
        float w2 = W[(2 * H + j) * E + e];
        float w3 = W[(3 * H + j) * E + e];
        #pragma unroll
        for (int v = 0; v < 16; v++) {
            float x = es[v * E + e];
            acc[0][v] += w0 * x; acc[1][v] += w1 * x;
            acc[2][v] += w2 * x; acc[3][v] += w3 * x;
        }
    }
    for (int v = 0; v < 16; v++)
        #pragma unroll
        for (int q = 0; q < 4; q++)
            pe[(vb * 16 + v) * G4 + q * H + j] = acc[q][v];
}

/* streamed-W layout: wstr[(d*WSTR + g)*1024 + r] = {W_d[r][92+4g .. +3]} */
__global__ __launch_bounds__(256) void k_prep(const float* __restrict__ whhf,
                                              const float* __restrict__ whhb,
                                              char* __restrict__ ws) {
    int tid = blockIdx.x * 256 + threadIdx.x;   /* 2*41*1024 = 83968 */
    if (tid >= 2 * WSTR * 1024) return;
    int d   = tid >= WSTR * 1024;
    int idx = d ? tid - WSTR * 1024 : tid;
    int g = idx >> 10, r = idx & 1023;
    const float* whh = d ? whhb : whhf;
    float4* wstr = (float4*)(ws + OFF_WSTREAM);
    const float4* src = (const float4*)(whh + (size_t)r * H + 4 * (WREG + WLDS));
    wstr[((size_t)(d * WSTR + g) << 10) + r] = src[g];
}

/* zero the pair-exchange flags (only launched when the pair path is used) */
__global__ __launch_bounds__(256) void k_zflg(char* __restrict__ ws) {
    ((int*)(ws + OFF_FLG))[threadIdx.x] = 0;
}

/* ---------- R8 pair kernel: NB=2 with unit-half row split ----------
   256 blocks x 512 thr. q = blk>>7 (unit half), job = blk&127, d = job>>6,
   p = job&63, batches 2p/2p+1. Thread t: gq = t>>7 (gate), uo = t&127
   (unit offset); row = gq*256 + q*128 + uo. One row, BOTH batches:
   512 FMA/thread, W bytes/step HALVED chip-wide vs R7.
   W per row: groups 0..19 pinned live (80 VGPR @ 2 waves/SIMD budget 256),
   20..22 LDS slab (own 512 rows), 23..63 streamed (wstr slots 0..40).
   Phases split by h-half dependence; partner h arrives via agent-scope
   hx/flag exchange (parity double-buffered), hidden under the own-h phase.
   Emission: R7-style deferred one step, q==0 blocks only. */
__global__ __attribute__((amdgpu_flat_work_group_size(512, 512), amdgpu_waves_per_eu(2, 2)))
void k_lstm2(const int* __restrict__ data,
             const float* __restrict__ whhf,
             const float* __restrict__ whhb,
             const float* __restrict__ mlpW,
             char* __restrict__ ws) {
    int blk = blockIdx.x;
    int q = blk >> 7, job = blk & 127;
    int d = job >> 6, p = job & 63;
    int b0 = 2 * p, b1 = b0 + 1;
    const float* whh = d ? whhb : whhf;
    const float* pe  = (const float*)(ws + (d ? OFF_PEMB_B : OFF_PEMB_F));
    float* emdst = (float*)(ws + (d ? OFF_EMB : OFF_EMF));
    const float4* wstr = (const float4*)(ws + OFF_WSTREAM) + ((size_t)(d * WSTR) << 10);
    float* hxf = (float*)(ws + OFF_HX);
    int* flg = (int*)(ws + OFF_FLG);
    int* flg_self = flg + job * 2 + q;
    int* flg_part = flg + job * 2 + (1 - q);

    __shared__ __align__(16) float hs[2][H];   /* [batch][unit] full h, 2 KB */
    __shared__ float4 sW[WLDS << 9];           /* 3 x 512 rows, 24 KB */
    __shared__ float  gbuf[2 * 512];           /* [batch][localrow], 4 KB */
    __shared__ int    toks[2][S];              /* 4 KB */

    int t = threadIdx.x;                       /* 0..511 */
    int gq = t >> 7, uo = t & 127;
    int row = gq * 256 + q * 128 + uo;
    int oth = 1 - q;

    const float4* wrow = (const float4*)(whh + (size_t)row * H);
    float4 wP[WREG];
    #pragma unroll
    for (int g = 0; g < WREG; g++) wP[g] = wrow[g];
    #pragma unroll
    for (int g = 0; g < WREG; g++)
        asm volatile("" : "+v"(wP[g].x), "+v"(wP[g].y), "+v"(wP[g].z), "+v"(wP[g].w));

    #pragma unroll
    for (int j = 0; j < WLDS; j++) sW[(j << 9) + t] = wrow[WREG + j];

    toks[0][t] = data[b0 * S + t];             /* S == 512 == blockDim */
    toks[1][t] = data[b1 * S + t];

    /* emission coefs: threads 0..287 (bi, tag tt, slice el), q==0 only */
    float mwE[16];
    int ebi = t / 144, erem = t - ebi * 144, ett = erem >> 4, eel = erem & 15;
    if (q == 0 && t < 288) {
        #pragma unroll
        for (int k = 0; k < 16; k++)
            mwE[k] = mlpW[ett * (2 * H) + d * H + eel + 16 * k];
    }
    if (t < 256) { hs[0][t] = 0.0f; hs[1][t] = 0.0f; }
    float cst = 0.0f;                          /* cell state (t<256: bi=t>>7, uo) */
    __syncthreads();

    const float4* h40 = (const float4*)&hs[0][0];
    const float4* h41 = (const float4*)&hs[1][0];
    const float4* wsp = wstr + row;

    float pf0, pf1;
    {
        int sp0 = d ? (S - 1) : 0;
        pf0 = pe[((size_t)toks[0][sp0] << 10) + row];
        pf1 = pe[((size_t)toks[1][sp0] << 10) + row];
    }

    int spPrev = 0;
    for (int ss = 0; ss < S; ss++) {
        int sp = d ? (S - 1 - ss) : ss;
        float a0 = pf0, a1 = pf1;
        if (ss + 1 < S) {
            int spn = d ? (S - 2 - ss) : (ss + 1);
            pf0 = pe[((size_t)toks[0][spn] << 10) + row];
            pf1 = pe[((size_t)toks[1][spn] << 10) + row];
        }

        /* ---- phase 1: groups whose h is OWN half ---- */
        if (q == 0) {
            /* pin 0..19 + LDS 20..22 + stream slots 0..8 (h groups 0..31) */
            #pragma unroll
            for (int g = 0; g < WREG; g++) {
                float4 h0 = h40[g], h1 = h41[g], w = wP[g];
                a0 = fmaf(w.x, h0.x, a0);  a1 = fmaf(w.x, h1.x, a1);
                a0 = fmaf(w.y, h0.y, a0);  a1 = fmaf(w.y, h1.y, a1);
                a0 = fmaf(w.z, h0.z, a0);  a1 = fmaf(w.z, h1.z, a1);
                a0 = fmaf(w.w, h0.w, a0);  a1 = fmaf(w.w, h1.w, a1);
            }
            #pragma unroll
            for (int j = 0; j < WLDS; j++) {
                float4 h0 = h40[WREG + j], h1 = h41[WREG + j], w = sW[(j << 9) + t];
                a0 = fmaf(w.x, h0.x, a0);  a1 = fmaf(w.x, h1.x, a1);
                a0 = fmaf(w.y, h0.y, a0);  a1 = fmaf(w.y, h1.y, a1);
                a0 = fmaf(w.z, h0.z, a0);  a1 = fmaf(w.z, h1.z, a1);
                a0 = fmaf(w.w, h0.w, a0);  a1 = fmaf(w.w, h1.w, a1);
            }
            #pragma unroll 3
            for (int s2 = 0; s2 < 9; s2++) {
                float4 w = wsp[(size_t)s2 << 10];
                float4 h0 = h40[23 + s2], h1 = h41[23 + s2];
                a0 = fmaf(w.x, h0.x, a0);  a1 = fmaf(w.x, h1.x, a1);
                a0 = fmaf(w.y, h0.y, a0);  a1 = fmaf(w.y, h1.y, a1);
                a0 = fmaf(w.z, h0.z, a0);  a1 = fmaf(w.z, h1.z, a1);
                a0 = fmaf(w.w, h0.w, a0);  a1 = fmaf(w.w, h1.w, a1);
            }
        } else {
            /* stream slots 9..40 (h groups 32..63) */
            #pragma unroll 4
            for (int s2 = 9; s2 < 41; s2++) {
                float4 w = wsp[(size_t)s2 << 10];
                float4 h0 = h40[23 + s2], h1 = h41[23 + s2];
                a0 = fmaf(w.x, h0.x, a0);  a1 = fmaf(w.x, h1.x, a1);
                a0 = fmaf(w.y, h0.y, a0);  a1 = fmaf(w.y, h1.y, a1);
                a0 = fmaf(w.z, h0.z, a0);  a1 = fmaf(w.z, h1.z, a1);
                a0 = fmaf(w.w, h0.w, a0);  a1 = fmaf(w.w, h1.w, a1);
            }
        }

        /* ---- partner h exchange (h(ss-1) other half) ---- */
        if (ss > 0) {
            if (t == 0) {
                while (__hip_atomic_load(flg_part, __ATOMIC_ACQUIRE,
                                         __HIP_MEMORY_SCOPE_AGENT) < ss)
                    __builtin_amdgcn_s_sleep(1);
            }
            __syncthreads();
            if (t < 256) {
                int bi = t >> 7, u2 = t & 127;
                int idx = ((((((ss - 1) & 1) * 128 + job) * 2 + oth) * 2 + bi) << 7) + u2;
                hs[bi][oth * 128 + u2] =
                    __hip_atomic_load(hxf + idx, __ATOMIC_RELAXED, __HIP_MEMORY_SCOPE_AGENT);
            }
            __syncthreads();
            /* emission for step ss-1 (full h(ss-1) now in LDS), q==0 only */
            if (q == 0 && t < 288) {
                float v = 0.0f;
                #pragma unroll
                for (int k = 0; k < 16; k++) v = fmaf(hs[ebi][eel + 16 * k], mwE[k], v);
                v += __shfl_xor(v, 8, 16);
                v += __shfl_xor(v, 4, 16);
                v += __shfl_xor(v, 2, 16);
                v += __shfl_xor(v, 1, 16);
                if (eel == 0)
                    emdst[((size_t)(b0 + ebi) * S + spPrev) * T + ett] = v;
            }
        }

        /* ---- phase 2: groups whose h is OTHER half ---- */
        if (q == 0) {
            #pragma unroll 4
            for (int s2 = 9; s2 < 41; s2++) {
                float4 w = wsp[(size_t)s2 << 10];
                float4 h0 = h40[23 + s2], h1 = h41[23 + s2];
                a0 = fmaf(w.x, h0.x, a0);  a1 = fmaf(w.x, h1.x, a1);
                a0 = fmaf(w.y, h0.y, a0);  a1 = fmaf(w.y, h1.y, a1);
                a0 = fmaf(w.z, h0.z, a0);  a1 = fmaf(w.z, h1.z, a1);
                a0 = fmaf(w.w, h0.w, a0);  a1 = fmaf(w.w, h1.w, a1);
            }
        } else {
            #pragma unroll
            for (int g = 0; g < WREG; g++) {
                float4 h0 = h40[g], h1 = h41[g], w = wP[g];
                a0 = fmaf(w.x, h0.x, a0);  a1 = fmaf(w.x, h1.x, a1);
                a0 = fmaf(w.y, h0.y, a0);  a1 = fmaf(w.y, h1.y, a1);
                a0 = fmaf(w.z, h0.z, a0);  a1 = fmaf(w.z, h1.z, a1);
                a0 = fmaf(w.w, h0.w, a0);  a1 = fmaf(w.w, h1.w, a1);
            }
            #pragma unroll
            for (int j = 0; j < WLDS; j++) {
                float4 h0 = h40[WREG + j], h1 = h41[WREG + j], w = sW[(j << 9) + t];
                a0 = fmaf(w.x, h0.x, a0);  a1 = fmaf(w.x, h1.x, a1);
                a0 = fmaf(w.y, h0.y, a0);  a1 = fmaf(w.y, h1.y, a1);
                a0 = fmaf(w.z, h0.z, a0);  a1 = fmaf(w.z, h1.z, a1);
                a0 = fmaf(w.w, h0.w, a0);  a1 = fmaf(w.w, h1.w, a1);
            }
            #pragma unroll 3
            for (int s2 = 0; s2 < 9; s2++) {
                float4 w = wsp[(size_t)s2 << 10];
                float4 h0 = h40[23 + s2], h1 = h41[23 + s2];
                a0 = fmaf(w.x, h0.x, a0);  a1 = fmaf(w.x, h1.x, a1);
                a0 = fmaf(w.y, h0.y, a0);  a1 = fmaf(w.y, h1.y, a1);
                a0 = fmaf(w.z, h0.z, a0);  a1 = fmaf(w.z, h1.z, a1);
                a0 = fmaf(w.w, h0.w, a0);  a1 = fmaf(w.w, h1.w, a1);
            }
        }

        gbuf[t] = a0;            /* batch0 partial for local row t */
        gbuf[512 + t] = a1;      /* batch1 */
        __syncthreads();   /* B1: gates complete, hs reads done */

        if (t < 256) {
            int bi = t >> 7, u2 = t & 127;
            float gi = gbuf[bi * 512 + u2],       gf = gbuf[bi * 512 + 128 + u2];
            float gg = gbuf[bi * 512 + 256 + u2], go = gbuf[bi * 512 + 384 + u2];
            float ig = sigf(gi), fg = sigf(gf), tg = tanhf(gg), og = sigf(go);
            cst = fg * cst + ig * tg;
            float hn = og * tanhf(cst);
            hs[bi][q * 128 + u2] = hn;
            int idx = (((((ss & 1) * 128 + job) * 2 + q) * 2 + bi) << 7) + u2;
            __hip_atomic_store(hxf + idx, hn, __ATOMIC_RELAXED, __HIP_MEMORY_SCOPE_AGENT);
        }
        __syncthreads();   /* B2: hs own half + hx stores issued */
        if (t == 0) {
            __threadfence();
            __hip_atomic_store(flg_self, ss + 1, __ATOMIC_RELEASE, __HIP_MEMORY_SCOPE_AGENT);
        }
        spPrev = sp;
    }

    /* final emission round: need full h(S-1) */
    if (t == 0) {
        while (__hip_atomic_load(flg_part, __ATOMIC_ACQUIRE,
                                 __HIP_MEMORY_SCOPE_AGENT) < S)
            __builtin_amdgcn_s_sleep(1);
    }
    __syncthreads();
    if (t < 256) {
        int bi = t >> 7, u2 = t & 127;
        int idx = ((((((S - 1) & 1) * 128 + job) * 2 + oth) * 2 + bi) << 7) + u2;
        hs[bi][oth * 128 + u2] =
            __hip_atomic_load(hxf + idx, __ATOMIC_RELAXED, __HIP_MEMORY_SCOPE_AGENT);
    }
    __syncthreads();
    if (q == 0 && t < 288) {
        float v = 0.0f;
        #pragma unroll
        for (int k = 0; k < 16; k++) v = fmaf(hs[ebi][eel + 16 * k], mwE[k], v);
        v += __shfl_xor(v, 8, 16);
        v += __shfl_xor(v, 4, 16);
        v += __shfl_xor(v, 2, 16);
        v += __shfl_xor(v, 1, 16);
        if (eel == 0)
            emdst[((size_t)(b0 + ebi) * S + spPrev) * T + ett] = v;
    }
}

/* ---------- R7 fallback kernel (verified, 8.05us/step) ---------- */
__global__ __attribute__((amdgpu_flat_work_group_size(512, 512), amdgpu_waves_per_eu(2, 2)))
void k_lstm(const int* __restrict__ data,
            const float* __restrict__ whhf,
            const float* __restrict__ whhb,
            const float* __restrict__ mlpW,
            char* __restrict__ ws) {
    int blk = blockIdx.x;
    int d = blk >> 7, b = blk & 127;
    const float* whh = d ? whhb : whhf;
    const float* pe  = (const float*)(ws + (d ? OFF_PEMB_B : OFF_PEMB_F));
    float* emdst = (float*)(ws + (d ? OFF_EMB : OFF_EMF));
    const float4* wstr = (const float4*)(ws + OFF_WSTREAM) + ((size_t)(d * WSTR) << 10);

    __shared__ __align__(16) float hs[H];
    __shared__ float4 sW[WLDS << 10];
    __shared__ float  gbuf[G4];
    __shared__ int    toks[S];

    int t = threadIdx.x;
    int r0 = t, r1 = t + 512;

    const float4* wrow0 = (const float4*)(whh + (size_t)r0 * H);
    const float4* wrow1 = (const float4*)(whh + (size_t)r1 * H);
    float4 wA[WREG], wB[WREG];
    #pragma unroll
    for (int g = 0; g < WREG; g++) { wA[g] = wrow0[g]; wB[g] = wrow1[g]; }
    #pragma unroll
    for (int g = 0; g < WREG; g++) {
        asm volatile("" : "+v"(wA[g].x), "+v"(wA[g].y), "+v"(wA[g].z), "+v"(wA[g].w));
        asm volatile("" : "+v"(wB[g].x), "+v"(wB[g].y), "+v"(wB[g].z), "+v"(wB[g].w));
    }
    #pragma unroll
    for (int g = 0; g < WLDS; g++) {
        sW[(g << 10) + r0] = wrow0[WREG + g];
        sW[(g << 10) + r1] = wrow1[WREG + g];
    }

    toks[t] = data[b * S + t];

    float mwE[16];
    int tt = (t - 256) >> 4, el = (t - 256) & 15;
    if (t >= 256 && t < 256 + 16 * T) {
        #pragma unroll
        for (int k = 0; k < 16; k++)
            mwE[k] = mlpW[tt * (2 * H) + d * H + el + 16 * k];
    }
    if (t < H) hs[t] = 0.0f;
    float cst = 0.0f;
    __syncthreads();

    const float4* hs4 = (const float4*)hs;
    const float4* wsp0 = wstr + r0;
    const float4* wsp1 = wstr + r1;

    float pf0, pf1;
    {
        int sp0 = d ? (S - 1) : 0;
        size_t tok = (size_t)toks[sp0];
        pf0 = pe[(tok << 10) + r0];
        pf1 = pe[(tok << 10) + r1];
    }

    for (int ss = 0; ss < S; ss++) {
        int sp = d ? (S - 1 - ss) : ss;
        float acc0 = pf0, acc1 = pf1;
        if (ss + 1 < S) {
            int spn = d ? (S - 2 - ss) : (ss + 1);
            size_t tok = (size_t)toks[spn];
            pf0 = pe[(tok << 10) + r0];
            pf1 = pe[(tok << 10) + r1];
        }

        #pragma unroll
        for (int g = 0; g < WREG; g++) {
            float4 h4 = hs4[g];
            float4 a = wA[g], bb2 = wB[g];
            acc0 = fmaf(a.x, h4.x, acc0);  acc1 = fmaf(bb2.x, h4.x, acc1);
            acc0 = fmaf(a.y, h4.y, acc0);  acc1 = fmaf(bb2.y, h4.y, acc1);
            acc0 = fmaf(a.z, h4.z, acc0);  acc1 = fmaf(bb2.z, h4.z, acc1);
            acc0 = fmaf(a.w, h4.w, acc0);  acc1 = fmaf(bb2.w, h4.w, acc1);
        }
        #pragma unroll
        for (int g = 0; g < WLDS; g++) {
            float4 w0 = sW[(g << 10) + r0];
            float4 w1 = sW[(g << 10) + r1];
            float4 h4 = hs4[WREG + g];
            acc0 = fmaf(w0.x, h4.x, acc0);  acc1 = fmaf(w1.x, h4.x, acc1);
            acc0 = fmaf(w0.y, h4.y, acc0);  acc1 = fmaf(w1.y, h4.y, acc1);
            acc0 = fmaf(w0.z, h4.z, acc0);  acc1 = fmaf(w1.z, h4.z, acc1);
            acc0 = fmaf(w0.w, h4.w, acc0);  acc1 = fmaf(w1.w, h4.w, acc1);
        }
        #pragma unroll 4
        for (int g = 0; g < WSTR; g++) {
            float4 w0 = wsp0[(size_t)g << 10];
            float4 w1 = wsp1[(size_t)g << 10];
            float4 h4 = hs4[WREG + WLDS + g];
            acc0 = fmaf(w0.x, h4.x, acc0);  acc1 = fmaf(w1.x, h4.x, acc1);
            acc0 = fmaf(w0.y, h4.y, acc0);  acc1 = fmaf(w1.y, h4.y, acc1);
            acc0 = fmaf(w0.z, h4.z, acc0);  acc1 = fmaf(w1.z, h4.z, acc1);
            acc0 = fmaf(w0.w, h4.w, acc0);  acc1 = fmaf(w1.w, h4.w, acc1);
        }
        gbuf[r0] = acc0;
        gbuf[r1] = acc1;
        __syncthreads();

        if (t < 256) {
            float gi = gbuf[t], gf = gbuf[H + t], gg = gbuf[2 * H + t], go = gbuf[3 * H + t];
            float ig = sigf(gi), fg = sigf(gf), tg = tanhf(gg), og = sigf(go);
            cst = fg * cst + ig * tg;
            float hn = og * tanhf(cst);
            hs[t] = hn;
        }
        __syncthreads();

        if (t >= 256 && t < 256 + 16 * T) {
            float v = 0.0f;
            #pragma unroll
            for (int k = 0; k < 16; k++) v = fmaf(hs[el + 16 * k], mwE[k], v);
            v += __shfl_xor(v, 8, 16);
            v += __shfl_xor(v, 4, 16);
            v += __shfl_xor(v, 2, 16);
            v += __shfl_xor(v, 1, 16);
            if (el == 0)
                emdst[((size_t)b * S + sp) * T + tt] = v;
        }
    }
}

/* Viterbi forward: one wave per batch, lane t = tag. */
__global__ __launch_bounds__(64) void k_vit(const int* __restrict__ data,
                                            const float* __restrict__ strans,
                                            const float* __restrict__ trans,
                                            const float* __restrict__ etrans,
                                            const float* __restrict__ mlpb,
                                            float* __restrict__ out,
                                            char* __restrict__ ws) {
    int b = blockIdx.x, t = threadIdx.x;
    const float* emf = (const float*)(ws + OFF_EMF);
    const float* emb = (const float*)(ws + OFF_EMB);
    char* bp = ws + OFF_BP;
    int*  lt = (int*)(ws + OFF_LT);
    bool act = t < T;

    float trp[T];
    float mb = 0.0f;
    if (act) {
        #pragma unroll
        for (int p = 0; p < T; p++) trp[p] = trans[p * T + t];
        mb = mlpb[t];
    }
    float score = -1e30f;
    if (act) score = strans[t] + emf[(b * S) * T + t] + emb[(b * S) * T + t] + mb;

    for (int s = 1; s < S; s++) {
        float e = 0.0f;
        if (act) e = emf[(b * S + s) * T + t] + emb[(b * S + s) * T + t] + mb;
        float best = __shfl(score, 0, 64) + trp[0];
        int bpi = 0;
        #pragma unroll
        for (int p = 1; p < T; p++) {
            float cand = __shfl(score, p, 64) + trp[p];
            if (cand > best) { best = cand; bpi = p; }
        }
        int m = data[b * S + s] != 0;
        if (act) {
            score = m ? (best + e) : score;
            bp[((size_t)(s - 1) * B + b) * 16 + t] = (char)bpi;
        }
    }
    float fin = act ? score + etrans[t] : -1e30f;
    float bv = __shfl(fin, 0, 64);
    int bi = 0;
    #pragma unroll
    for (int p = 1; p < T; p++) {
        float v = __shfl(fin, p, 64);
        if (v > bv) { bv = v; bi = p; }
    }
    if (t == 0) { out[B * S + b] = bv; lt[b] = bi; }
}

/* Backtrack */
__global__ __launch_bounds__(128) void k_back(const int* __restrict__ data, char* __restrict__ ws) {
    int b = threadIdx.x;
    const int4* bp4 = (const int4*)(ws + OFF_BP);
    const int*  lt  = (const int*)(ws + OFF_LT);
    int* pt = (int*)(ws + OFF_PT);
    int tag = lt[b];
    pt[(S - 1) * B + b] = tag;
    for (int p = S - 2; p >= 0; p--) {
        int4 r = bp4[(size_t)p * B + b];
        int m = data[b * S + p + 1] != 0;
        unsigned w = (unsigned)(tag < 8 ? (tag < 4 ? r.x : r.y) : r.z);
        int nt = (int)((w >> ((tag & 3) * 8)) & 0xff);
        tag = m ? nt : tag;
        pt[p * B + b] = tag;
    }
}

/* paths -> float output with mask zeroing */
__global__ __launch_bounds__(256) void k_fin(const int* __restrict__ data,
                                             float* __restrict__ out,
                                             const char* __restrict__ ws) {
    int tid = blockIdx.x * 256 + threadIdx.x;   /* 65536 */
    const int* pt = (const int*)(ws + OFF_PT);
    int b = tid >> 9, p = tid & 511;
    out[tid] = (data[tid] != 0) ? (float)pt[p * B + b] : 0.0f;
}

extern "C" void kernel_launch(void* const* d_in, const int* in_sizes, int n_in,
                              void* d_out, int out_size, void* d_ws, size_t ws_size,
                              hipStream_t stream) {
    const int*   data = (const int*)d_in[0];
    /* d_in[1] = mask (bool) — unused; mask == (data != 0) */
    const float* emb  = (const float*)d_in[2];
    const float* wihf = (const float*)d_in[3];
    const float* whhf = (const float*)d_in[4];
    const float* bf   = (const float*)d_in[5];
    const float* wihb = (const float*)d_in[6];
    const float* whhb = (const float*)d_in[7];
    const float* bb   = (const float*)d_in[8];
    const float* mlpW = (const float*)d_in[9];
    const float* mlpb = (const float*)d_in[10];
    const float* st   = (const float*)d_in[11];
    const float* tr   = (const float*)d_in[12];
    const float* et   = (const float*)d_in[13];
    float* out = (float*)d_out;
    char*  ws  = (char*)d_ws;

    int pair_ok = (ws_size >= WS_NEED);

    hipLaunchKernelGGL(k_pemb, dim3(750),  dim3(256), 0, stream, emb, wihf, bf, wihb, bb, ws);
    hipLaunchKernelGGL(k_prep, dim3(328),  dim3(256), 0, stream, whhf, whhb, ws);
    if (pair_ok) {
        hipLaunchKernelGGL(k_zflg,  dim3(1),   dim3(256), 0, stream, ws);
        hipLaunchKernelGGL(k_lstm2, dim3(256), dim3(512), 0, stream, data, whhf, whhb, mlpW, ws);
    } else {
        hipLaunchKernelGGL(k_lstm,  dim3(256), dim3(512), 0, stream, data, whhf, whhb, mlpW, ws);
    }
    hipLaunchKernelGGL(k_vit,  dim3(128),  dim3(64),  0, stream, data, st, tr, et, mlpb, out, ws);
    hipLaunchKernelGGL(k_back, dim3(1),    dim3(128), 0, stream, data, ws);
    hipLaunchKernelGGL(k_fin,  dim3(256),  dim3(256), 0, stream, data, out, ws);
}

// Round 9
// 4166.573 us; speedup vs baseline: 2.1987x; 2.1987x over previous
//
#include <hip/hip_runtime.h>
#include <math.h>
#include <stdint.h>

#define B 128
#define S 512
#define V 6000
#define E 100
#define H 256
#define G4 1024   /* 4*H */
#define T 9

/* W column split (float4 k-groups, 64 total = 256 cols per row)
   R9 = R7 exactly (verified 4167us total, 8.05us/step k_lstm).
   Session ledger closes all alternatives:
   - NB=2 fat block (R1 spill / R2 1-wave latency / R3 idle-CU wash)
   - LDS migration of stream W (R5: LDS pipe is the contended one)
   - k-split with scattered reloads on half the waves (R6 imbalance)
   - per-step cross-block h exchange (R8: coherence path bypasses L2 ->
     +280 MB HBM traffic, 2.2x slower). Non-coherent per-XCD L2s make
     any per-step inter-CU sharing unaffordable.
   - register residency >~130 VGPR: allocator refuses in 4 variants.
   R7 structure = 90% of aggregate-L2 roofline for this recurrence. */
#define WREG 20            /* cols [0,80): deep-pipelined per-step reloads (asm pin) */
#define WLDS 3             /* cols [80,92) in LDS slab (48 KB) */
#define WSTR 41            /* cols [92,256) streamed k-major (656 KB/step/dir) */

/* workspace byte offsets (256-aligned) */
#define OFF_PEMB_F 0u
#define PEMB_BYTES (V*G4*4u)                    /* 24,576,000 */
#define OFF_PEMB_B (OFF_PEMB_F + PEMB_BYTES)
#define OFF_EMF    (OFF_PEMB_B + PEMB_BYTES)    /* 49,152,000 */
#define EM_BYTES   (B*S*T*4u)                   /* 2,359,296 */
#define OFF_EMB    (OFF_EMF + EM_BYTES)
#define OFF_BP     (OFF_EMB + EM_BYTES)         /* 53,870,592 */
#define BP_BYTES   ((S-1)*B*16u)                /* 1,046,528 */
#define OFF_LT     (OFF_BP + BP_BYTES)
#define OFF_PT     (OFF_LT + 512u)
/* Streamed-W (2 dirs x 41 groups x 1024 rows x 16 B = 1,343,488 B) OVERLAYS
   the BP/LT/PT region: k_prep writes it and k_lstm reads it strictly BEFORE
   k_vit/k_back write BP/LT/PT (stream-ordered). */
#define OFF_WSTREAM OFF_BP

__device__ __forceinline__ float sigf(float x) { return 1.0f / (1.0f + expf(-x)); }

/* pemb[v][g4] = bias[g4] + sum_e emb[v][e] * W_ih[g4][e],  g4 = q*H + j */
__global__ __launch_bounds__(256) void k_pemb(const float* __restrict__ emb,
                                              const float* __restrict__ wf, const float* __restrict__ bf,
                                              const float* __restrict__ wb, const float* __restrict__ bb,
                                              char* __restrict__ ws) {
    int blk = blockIdx.x;                   /* 0..749 */
    int d   = blk >= 375;
    int vb  = d ? blk - 375 : blk;
    const float* W    = d ? wb : wf;
    const float* bias = d ? bb : bf;
    float* pe = (float*)(ws + (d ? OFF_PEMB_B : OFF_PEMB_F));

    __shared__ float es[16 * E];
    for (int i = threadIdx.x; i < 16 * E; i += 256) es[i] = emb[vb * 16 * E + i];
    __syncthreads();

    int j = threadIdx.x;
    float acc[4][16];
    #pragma unroll
    for (int q = 0; q < 4; q++) {
        float bq = bias[q * H + j];
        #pragma unroll
        for (int v = 0; v < 16; v++) acc[q][v] = bq;
    }
    for (int e = 0; e < E; e++) {
        float w0 = W[(0 * H + j) * E + e];
        float w1 = W[(1 * H + j) * E + e];
        float w2 = W[(2 * H + j) * E + e];
        float w3 = W[(3 * H + j) * E + e];
        #pragma unroll
        for (int v = 0; v < 16; v++) {
            float x = es[v * E + e];
            acc[0][v] += w0 * x; acc[1][v] += w1 * x;
            acc[2][v] += w2 * x; acc[3][v] += w3 * x;
        }
    }
    for (int v = 0; v < 16; v++)
        #pragma unroll
        for (int q = 0; q < 4; q++)
            pe[(vb * 16 + v) * G4 + q * H + j] = acc[q][v];
}

/* streamed-W layout: wstr[(d*WSTR + g)*1024 + r] = {W_d[r][92+4g .. +3]}
   -> per step, lane r loads consecutive float4 (coalesced 1 KB/wave-inst) */
__global__ __launch_bounds__(256) void k_prep(const float* __restrict__ whhf,
                                              const float* __restrict__ whhb,
                                              char* __restrict__ ws) {
    int tid = blockIdx.x * 256 + threadIdx.x;   /* 2*41*1024 = 83968 */
    if (tid >= 2 * WSTR * 1024) return;
    int d   = tid >= WSTR * 1024;
    int idx = d ? tid - WSTR * 1024 : tid;
    int g = idx >> 10, r = idx & 1023;
    const float* whh = d ? whhb : whhf;
    float4* wstr = (float4*)(ws + OFF_WSTREAM);
    const float4* src = (const float4*)(whh + (size_t)r * H + 4 * (WREG + WLDS));
    wstr[((size_t)(d * WSTR + g) << 10) + r] = src[g];
}

/* Single-CU LSTM: 256 blocks (dir d = blk>>7, batch b = blk&127) x 512 thr.
   Thread t owns gate rows t and t+512. Per row: cols [0,80) asm-pinned loads
   (deep load pipeline), [80,92) in LDS, [92,256) streamed coalesced from L2.
   Emission dot-products on threads 256..399 AFTER B2 (reading hs),
   overlapping the next step's matvec of waves 0-3. */
__global__ __attribute__((amdgpu_flat_work_group_size(512, 512), amdgpu_waves_per_eu(2, 2)))
void k_lstm(const int* __restrict__ data,
            const float* __restrict__ whhf,
            const float* __restrict__ whhb,
            const float* __restrict__ mlpW,
            char* __restrict__ ws) {
    int blk = blockIdx.x;
    int d = blk >> 7, b = blk & 127;
    const float* whh = d ? whhb : whhf;
    const float* pe  = (const float*)(ws + (d ? OFF_PEMB_B : OFF_PEMB_F));
    float* emdst = (float*)(ws + (d ? OFF_EMB : OFF_EMF));
    const float4* wstr = (const float4*)(ws + OFF_WSTREAM) + ((size_t)(d * WSTR) << 10);

    __shared__ __align__(16) float hs[H];      /* h_prev, 1 KB */
    __shared__ float4 sW[WLDS << 10];          /* 48 KB */
    __shared__ float  gbuf[G4];                /* 4 KB */
    __shared__ int    toks[S];                 /* 2 KB */

    int t = threadIdx.x;                       /* 0..511 */
    int r0 = t, r1 = t + 512;

    const float4* wrow0 = (const float4*)(whh + (size_t)r0 * H);
    const float4* wrow1 = (const float4*)(whh + (size_t)r1 * H);
    float4 wA[WREG], wB[WREG];
    #pragma unroll
    for (int g = 0; g < WREG; g++) { wA[g] = wrow0[g]; wB[g] = wrow1[g]; }
    /* pin: consume the loads pre-loop; keeps a deep load pipeline live */
    #pragma unroll
    for (int g = 0; g < WREG; g++) {
        asm volatile("" : "+v"(wA[g].x), "+v"(wA[g].y), "+v"(wA[g].z), "+v"(wA[g].w));
        asm volatile("" : "+v"(wB[g].x), "+v"(wB[g].y), "+v"(wB[g].z), "+v"(wB[g].w));
    }
    #pragma unroll
    for (int g = 0; g < WLDS; g++) {
        sW[(g << 10) + r0] = wrow0[WREG + g];
        sW[(g << 10) + r1] = wrow1[WREG + g];
    }

    toks[t] = data[b * S + t];                 /* S == 512 == blockDim */

    /* emission operands: threads 256..399 = tag tt, slice el */
    float mwE[16];
    int tt = (t - 256) >> 4, el = (t - 256) & 15;
    if (t >= 256 && t < 256 + 16 * T) {
        #pragma unroll
        for (int k = 0; k < 16; k++)
            mwE[k] = mlpW[tt * (2 * H) + d * H + el + 16 * k];
    }
    if (t < H) hs[t] = 0.0f;
    float cst = 0.0f;
    __syncthreads();

    const float4* hs4 = (const float4*)hs;
    const float4* wsp0 = wstr + r0;
    const float4* wsp1 = wstr + r1;

    float pf0, pf1;
    {
        int sp0 = d ? (S - 1) : 0;
        size_t tok = (size_t)toks[sp0];
        pf0 = pe[(tok << 10) + r0];
        pf1 = pe[(tok << 10) + r1];
    }

    for (int ss = 0; ss < S; ss++) {
        int sp = d ? (S - 1 - ss) : ss;
        float acc0 = pf0, acc1 = pf1;
        if (ss + 1 < S) {
            int spn = d ? (S - 2 - ss) : (ss + 1);
            size_t tok = (size_t)toks[spn];
            pf0 = pe[(tok << 10) + r0];
            pf1 = pe[(tok << 10) + r1];
        }

        /* "register"-W phase: cols 0..79 */
        #pragma unroll
        for (int g = 0; g < WREG; g++) {
            float4 h4 = hs4[g];
            float4 a = wA[g], bb2 = wB[g];
            acc0 = fmaf(a.x, h4.x, acc0);  acc1 = fmaf(bb2.x, h4.x, acc1);
            acc0 = fmaf(a.y, h4.y, acc0);  acc1 = fmaf(bb2.y, h4.y, acc1);
            acc0 = fmaf(a.z, h4.z, acc0);  acc1 = fmaf(bb2.z, h4.z, acc1);
            acc0 = fmaf(a.w, h4.w, acc0);  acc1 = fmaf(bb2.w, h4.w, acc1);
        }
        /* LDS-W phase: cols 80..91 */
        #pragma unroll
        for (int g = 0; g < WLDS; g++) {
            float4 w0 = sW[(g << 10) + r0];
            float4 w1 = sW[(g << 10) + r1];
            float4 h4 = hs4[WREG + g];
            acc0 = fmaf(w0.x, h4.x, acc0);  acc1 = fmaf(w1.x, h4.x, acc1);
            acc0 = fmaf(w0.y, h4.y, acc0);  acc1 = fmaf(w1.y, h4.y, acc1);
            acc0 = fmaf(w0.z, h4.z, acc0);  acc1 = fmaf(w1.z, h4.z, acc1);
            acc0 = fmaf(w0.w, h4.w, acc0);  acc1 = fmaf(w1.w, h4.w, acc1);
        }
        /* streamed phase: cols 92..255 (bounded pipelining via unroll 4) */
        #pragma unroll 4
        for (int g = 0; g < WSTR; g++) {
            float4 w0 = wsp0[(size_t)g << 10];
            float4 w1 = wsp1[(size_t)g << 10];
            float4 h4 = hs4[WREG + WLDS + g];
            acc0 = fmaf(w0.x, h4.x, acc0);  acc1 = fmaf(w1.x, h4.x, acc1);
            acc0 = fmaf(w0.y, h4.y, acc0);  acc1 = fmaf(w1.y, h4.y, acc1);
            acc0 = fmaf(w0.z, h4.z, acc0);  acc1 = fmaf(w1.z, h4.z, acc1);
            acc0 = fmaf(w0.w, h4.w, acc0);  acc1 = fmaf(w1.w, h4.w, acc1);
        }
        gbuf[r0] = acc0;
        gbuf[r1] = acc1;
        __syncthreads();   /* B1: gates complete, hs reads done */

        if (t < 256) {
            float gi = gbuf[t], gf = gbuf[H + t], gg = gbuf[2 * H + t], go = gbuf[3 * H + t];
            float ig = sigf(gi), fg = sigf(gf), tg = tanhf(gg), og = sigf(go);
            cst = fg * cst + ig * tg;
            float hn = og * tanhf(cst);
            hs[t] = hn;
        }
        __syncthreads();   /* B2: hs updated */

        /* emission on otherwise-idle threads 256..399, overlapping the
           next matvec of waves 0-3. Reads hs (published by B2); finishes
           before these waves reach next B1, which gates the next hs write. */
        if (t >= 256 && t < 256 + 16 * T) {
            float v = 0.0f;
            #pragma unroll
            for (int k = 0; k < 16; k++) v = fmaf(hs[el + 16 * k], mwE[k], v);
            v += __shfl_xor(v, 8, 16);
            v += __shfl_xor(v, 4, 16);
            v += __shfl_xor(v, 2, 16);
            v += __shfl_xor(v, 1, 16);
            if (el == 0)
                emdst[((size_t)b * S + sp) * T + tt] = v;
        }
    }
}

/* Viterbi forward: one wave per batch, lane t = tag. Strict-> ascending scan
   matches jnp.argmax first-index tie-breaking. */
__global__ __launch_bounds__(64) void k_vit(const int* __restrict__ data,
                                            const float* __restrict__ strans,
                                            const float* __restrict__ trans,
                                            const float* __restrict__ etrans,
                                            const float* __restrict__ mlpb,
                                            float* __restrict__ out,
                                            char* __restrict__ ws) {
    int b = blockIdx.x, t = threadIdx.x;
    const float* emf = (const float*)(ws + OFF_EMF);
    const float* emb = (const float*)(ws + OFF_EMB);
    char* bp = ws + OFF_BP;
    int*  lt = (int*)(ws + OFF_LT);
    bool act = t < T;

    float trp[T];
    float mb = 0.0f;
    if (act) {
        #pragma unroll
        for (int p = 0; p < T; p++) trp[p] = trans[p * T + t];
        mb = mlpb[t];
    }
    float score = -1e30f;
    if (act) score = strans[t] + emf[(b * S) * T + t] + emb[(b * S) * T + t] + mb;

    for (int s = 1; s < S; s++) {
        float e = 0.0f;
        if (act) e = emf[(b * S + s) * T + t] + emb[(b * S + s) * T + t] + mb;
        float best = __shfl(score, 0, 64) + trp[0];
        int bpi = 0;
        #pragma unroll
        for (int p = 1; p < T; p++) {
            float cand = __shfl(score, p, 64) + trp[p];
            if (cand > best) { best = cand; bpi = p; }
        }
        int m = data[b * S + s] != 0;
        if (act) {
            score = m ? (best + e) : score;
            bp[((size_t)(s - 1) * B + b) * 16 + t] = (char)bpi;
        }
    }
    float fin = act ? score + etrans[t] : -1e30f;
    float bv = __shfl(fin, 0, 64);
    int bi = 0;
    #pragma unroll
    for (int p = 1; p < T; p++) {
        float v = __shfl(fin, p, 64);
        if (v > bv) { bv = v; bi = p; }
    }
    if (t == 0) { out[B * S + b] = bv; lt[b] = bi; }
}

/* Backtrack: thread = batch; bp row address is tag-independent -> pipelined loads */
__global__ __launch_bounds__(128) void k_back(const int* __restrict__ data, char* __restrict__ ws) {
    int b = threadIdx.x;
    const int4* bp4 = (const int4*)(ws + OFF_BP);
    const int*  lt  = (const int*)(ws + OFF_LT);
    int* pt = (int*)(ws + OFF_PT);
    int tag = lt[b];
    pt[(S - 1) * B + b] = tag;
    for (int p = S - 2; p >= 0; p--) {
        int4 r = bp4[(size_t)p * B + b];
        int m = data[b * S + p + 1] != 0;
        unsigned w = (unsigned)(tag < 8 ? (tag < 4 ? r.x : r.y) : r.z);
        int nt = (int)((w >> ((tag & 3) * 8)) & 0xff);
        tag = m ? nt : tag;
        pt[p * B + b] = tag;
    }
}

/* paths -> float output with mask zeroing */
__global__ __launch_bounds__(256) void k_fin(const int* __restrict__ data,
                                             float* __restrict__ out,
                                             const char* __restrict__ ws) {
    int tid = blockIdx.x * 256 + threadIdx.x;   /* 65536 */
    const int* pt = (const int*)(ws + OFF_PT);
    int b = tid >> 9, p = tid & 511;
    out[tid] = (data[tid] != 0) ? (float)pt[p * B + b] : 0.0f;
}

extern "C" void kernel_launch(void* const* d_in, const int* in_sizes, int n_in,
                              void* d_out, int out_size, void* d_ws, size_t ws_size,
                              hipStream_t stream) {
    const int*   data = (const int*)d_in[0];
    /* d_in[1] = mask (bool) — unused; mask == (data != 0) */
    const float* emb  = (const float*)d_in[2];
    const float* wihf = (const float*)d_in[3];
    const float* whhf = (const float*)d_in[4];
    const float* bf   = (const float*)d_in[5];
    const float* wihb = (const float*)d_in[6];
    const float* whhb = (const float*)d_in[7];
    const float* bb   = (const float*)d_in[8];
    const float* mlpW = (const float*)d_in[9];
    const float* mlpb = (const float*)d_in[10];
    const float* st   = (const float*)d_in[11];
    const float* tr   = (const float*)d_in[12];
    const float* et   = (const float*)d_in[13];
    float* out = (float*)d_out;
    char*  ws  = (char*)d_ws;

    hipLaunchKernelGGL(k_pemb, dim3(750),  dim3(256), 0, stream, emb, wihf, bf, wihb, bb, ws);
    hipLaunchKernelGGL(k_prep, dim3(328),  dim3(256), 0, stream, whhf, whhb, ws);
    hipLaunchKernelGGL(k_lstm, dim3(256),  dim3(512), 0, stream, data, whhf, whhb, mlpW, ws);
    hipLaunchKernelGGL(k_vit,  dim3(128),  dim3(64),  0, stream, data, st, tr, et, mlpb, out, ws);
    hipLaunchKernelGGL(k_back, dim3(1),    dim3(128), 0, stream, data, ws);
    hipLaunchKernelGGL(k_fin,  dim3(256),  dim3(256), 0, stream, data, out, ws);
}